// Round 5
// baseline (356.454 us; speedup 1.0000x reference)
//
#include <hip/hip_runtime.h>
#include <stdint.h>

#define A_N 9
#define H_N 50
#define W_N 76
#define HW_N (H_N * W_N)      // 3800
#define N_PROP (A_N * HW_N)   // 34200
#define B_N 4
#define PRE_NMS 4000
#define POST_NMS 300
#define NMS_TH 0.7f
#define SORT_N 4096
#define MASK_WORDS 64
#define CAND_MAX 5120
#define NBINS 4096

typedef unsigned long long u64;

// ---------------------------------------------------------------------------
// Kernel A: decode + keys (a-major mapping -> all loads/stores coalesced).
// Key low word encodes REFERENCE index n_ref = hw*9 + a so descending key
// order == jax.lax.top_k order (stable lower-index-first tie-break).
// ---------------------------------------------------------------------------
__global__ void decode_kernel(const float* __restrict__ scores,
                              const float* __restrict__ deltas,
                              const float* __restrict__ im_info,
                              const float* __restrict__ anchors,
                              float4* __restrict__ boxes,
                              u64* __restrict__ keys,
                              unsigned* __restrict__ ghist) {
#pragma clang fp contract(off)
    int gid = blockIdx.x * blockDim.x + threadIdx.x;
    if (gid >= B_N * N_PROP) return;
    int b = gid / N_PROP;
    int r = gid - b * N_PROP;
    int a = r / HW_N;          // fixed across a wave
    int hw = r - a * HW_N;     // consecutive across lanes
    int hy = hw / W_N;
    int wx = hw - hy * W_N;

    float sx = (float)wx * 16.0f;
    float sy = (float)hy * 16.0f;
    float ax1 = anchors[a * 4 + 0] + sx;
    float ay1 = anchors[a * 4 + 1] + sy;
    float ax2 = anchors[a * 4 + 2] + sx;
    float ay2 = anchors[a * 4 + 3] + sy;
    float aw = ax2 - ax1 + 1.0f;
    float ah = ay2 - ay1 + 1.0f;
    float cx = ax1 + 0.5f * aw;
    float cy = ay1 + 0.5f * ah;

    const float* db = deltas + ((size_t)b * 36 + (size_t)a * 4) * HW_N + hw;
    float d0 = db[0];
    float d1 = db[HW_N];
    float d2 = db[2 * HW_N];
    float d3 = db[3 * HW_N];

    float pcx = d0 * aw + cx;
    float pcy = d1 * ah + cy;
    float pw  = expf(d2) * aw;
    float ph  = expf(d3) * ah;

    float x1 = pcx - 0.5f * pw;
    float y1 = pcy - 0.5f * ph;
    float x2 = pcx + 0.5f * pw;
    float y2 = pcy + 0.5f * ph;

    float xhi = im_info[b * 3 + 1] - 1.0f;
    float yhi = im_info[b * 3 + 0] - 1.0f;
    x1 = fminf(fmaxf(x1, 0.0f), xhi);
    y1 = fminf(fmaxf(y1, 0.0f), yhi);
    x2 = fminf(fmaxf(x2, 0.0f), xhi);
    y2 = fminf(fmaxf(y2, 0.0f), yhi);

    boxes[gid] = make_float4(x1, y1, x2, y2);  // a-major layout

    float s = scores[((size_t)b * A_N + a) * HW_N + hw];
    unsigned f = __float_as_uint(s);
    unsigned sk = f ^ ((f & 0x80000000u) ? 0xFFFFFFFFu : 0x80000000u);
    unsigned n_ref = (unsigned)(hw * A_N + a);
    u64 key = ((u64)sk << 32) | (unsigned)(~n_ref);
    keys[gid] = key;
    atomicAdd(&ghist[b * NBINS + (unsigned)(key >> 52)], 1u);
}

// ---------------------------------------------------------------------------
// Kernel B: threshold bucket T via two wave-level suffix scans.
// ---------------------------------------------------------------------------
__global__ __launch_bounds__(64) void findT_kernel(const unsigned* __restrict__ ghist,
                                                   int* __restrict__ Tout) {
    __shared__ unsigned h[NBINS];
    int b = blockIdx.x;
    int lane = threadIdx.x;  // 64
    for (int i = lane; i < NBINS; i += 64) h[i] = ghist[b * NBINS + i];
    __syncthreads();
    unsigned gsum = 0;
    for (int j = 0; j < 64; ++j) gsum += h[lane * 64 + j];
    unsigned s = gsum;
    for (int d = 1; d < 64; d <<= 1) {
        unsigned t = (unsigned)__shfl_down((int)s, d);
        if (lane + d < 64) s += t;
    }
    unsigned long long bal = __ballot(s >= PRE_NMS);
    int gstar = 63 - __builtin_clzll(bal);
    unsigned after = (gstar < 63) ? (unsigned)__builtin_amdgcn_readlane((int)s, gstar + 1) : 0u;
    unsigned R = PRE_NMS - after;
    unsigned s2 = h[gstar * 64 + lane];
    for (int d = 1; d < 64; d <<= 1) {
        unsigned t = (unsigned)__shfl_down((int)s2, d);
        if (lane + d < 64) s2 += t;
    }
    unsigned long long bal2 = __ballot(s2 >= R);
    int j = 63 - __builtin_clzll(bal2);
    if (lane == 0) Tout[b] = gstar * 64 + j;
}

// ---------------------------------------------------------------------------
// Kernel C: compact candidates; wave-aggregated atomic.
// ---------------------------------------------------------------------------
__global__ void compact_kernel(const u64* __restrict__ keys,
                               const int* __restrict__ T,
                               unsigned* __restrict__ cnt,
                               u64* __restrict__ cand) {
    int b = blockIdx.y;
    int n = blockIdx.x * 256 + threadIdx.x;
    bool pred = false;
    u64 k = 0ull;
    if (n < N_PROP) {
        k = keys[(size_t)b * N_PROP + n];
        pred = ((int)(unsigned)(k >> 52) >= T[b]);
    }
    unsigned long long m = __ballot(pred);
    if (m) {
        int lane = threadIdx.x & 63;
        int lead = __ffsll((unsigned long long)m) - 1;
        unsigned base = 0;
        if (lane == lead) base = atomicAdd(&cnt[b], (unsigned)__popcll(m));
        base = __shfl((int)base, lead);
        if (pred) {
            unsigned pos = base + (unsigned)__popcll(m & ((1ull << lane) - 1ull));
            if (pos < CAND_MAX) cand[(size_t)b * CAND_MAX + pos] = k;
        }
    }
}

// ---------------------------------------------------------------------------
// Kernel D: exact rank by pairwise count, 4-way j-split per candidate.
// ---------------------------------------------------------------------------
__global__ __launch_bounds__(256) void rank_scatter_kernel(
    const u64* __restrict__ cand,
    const unsigned* __restrict__ cnt,
    const float4* __restrict__ boxes,
    float4* __restrict__ sortedBoxes) {
    __shared__ u64 sk[256];
    int b = blockIdx.y;
    int tid = threadIdx.x;
    int ci = blockIdx.x * 64 + (tid >> 2);
    int q = tid & 3;
    int mc = (int)min(cnt[b], (unsigned)CAND_MAX);
    u64 my = (ci < mc) ? cand[(size_t)b * CAND_MAX + ci] : 0ull;
    int rank = 0;
    int nt = (mc + 255) >> 8;
    for (int t = 0; t < nt; ++t) {
        int j = t * 256 + tid;
        sk[tid] = (j < mc) ? cand[(size_t)b * CAND_MAX + j] : 0ull;
        __syncthreads();
#pragma unroll 16
        for (int c = 0; c < 64; ++c) {
            int cc = q * 64 + ((c + q * 17) & 63);
            rank += (sk[cc] > my) ? 1 : 0;
        }
        __syncthreads();
    }
    rank += __shfl_xor(rank, 1);
    rank += __shfl_xor(rank, 2);
    if (q == 0 && ci < mc && rank < PRE_NMS) {
        unsigned n_ref = ~(unsigned)(my & 0xFFFFFFFFull);
        unsigned a = n_ref % A_N;
        unsigned hw = n_ref / A_N;
        sortedBoxes[(size_t)b * SORT_N + rank] =
            boxes[(size_t)b * N_PROP + a * HW_N + hw];
    }
    if (q == 1) {
        int pi = blockIdx.x * 64 + (tid >> 2);
        if (pi >= PRE_NMS && pi < SORT_N)
            sortedBoxes[(size_t)b * SORT_N + pi] = make_float4(0.f, 0.f, 0.f, 0.f);
    }
}

// ---------------------------------------------------------------------------
// Kernel E: suppression bitmask -> BOTH column-major (for diag/carry columns,
// coalesced store) and row-major (for coalesced kept-row loads in the scan).
// Upper triangle only; unwritten lower-tri words are consumed only after
// their groups have already been decided (dead bits).
// ---------------------------------------------------------------------------
__global__ void iou_mask_kernel(const float4* __restrict__ sortedBoxes,
                                u64* __restrict__ colmaj,
                                u64* __restrict__ rowmaj) {
#pragma clang fp contract(off)
    int rc = blockIdx.x, cc = blockIdx.y, b = blockIdx.z;
    if (cc < rc) return;
    int t = threadIdx.x;
    __shared__ float4 colb[64];
    colb[t] = sortedBoxes[(size_t)b * SORT_N + cc * 64 + t];
    __syncthreads();
    int r = rc * 64 + t;
    float4 rb = sortedBoxes[(size_t)b * SORT_N + r];
    float rarea = (rb.z - rb.x) * (rb.w - rb.y);
    u64 word = 0ull;
    for (int c = 0; c < 64; ++c) {
        int j = cc * 64 + c;
        float4 cb = colb[c];
        float carea = (cb.z - cb.x) * (cb.w - cb.y);
        float ltx = fmaxf(rb.x, cb.x);
        float lty = fmaxf(rb.y, cb.y);
        float rbx = fminf(rb.z, cb.z);
        float rby = fminf(rb.w, cb.w);
        float iw = fmaxf(rbx - ltx, 0.0f);
        float ih = fmaxf(rby - lty, 0.0f);
        float inter = iw * ih;
        float iou = inter / (rarea + carea - inter + 1e-9f);
        if (iou > NMS_TH && j > r) word |= (1ull << c);
    }
    colmaj[((size_t)b * MASK_WORDS + cc) * SORT_N + r] = word;          // coalesced
    rowmaj[((size_t)b * SORT_N + r) * MASK_WORDS + cc] = word;          // scattered store (fire & forget)
}

// ---------------------------------------------------------------------------
// Kernel F: group-tile greedy scan. 256 threads/image: 4 waves preload
// diag + next-column into 64KB dynamic LDS, then wave 0 runs the serial
// scan with ONLY LDS/readlane on the decision path. Kept-row loads are
// coalesced row-major reads, deferred 2 groups (2x8 register generations;
// the 1-group gap covered by the in-register c1 carry).
// ---------------------------------------------------------------------------
__device__ inline u64 rl64(u64 v, int src) {
    unsigned lo = (unsigned)__builtin_amdgcn_readlane((int)(unsigned)(v & 0xFFFFFFFFull), src);
    unsigned hi = (unsigned)__builtin_amdgcn_readlane((int)(unsigned)(v >> 32), src);
    return ((u64)hi << 32) | lo;
}

__global__ __launch_bounds__(256) void nms_scan_kernel(
    const u64* __restrict__ colmaj,
    const u64* __restrict__ rowmaj,
    const float4* __restrict__ sortedBoxes,
    float* __restrict__ out) {
    extern __shared__ u64 lds[];           // 65536 B: diag[4096] + c1[4096]
    u64* ldsDiag = lds;
    u64* ldsC1 = lds + 4096;
    int b = blockIdx.x;
    int tid = threadIdx.x;
    int lane = tid & 63;
    int wid = tid >> 6;
    const u64* C = colmaj + (size_t)b * MASK_WORDS * SORT_N;
    const u64* R = rowmaj + (size_t)b * SORT_N * MASK_WORDS;

    // cooperative preload: diag word g and word g+1 over rows of group g
    for (int g = wid; g < 64; g += 4) {
        ldsDiag[(g << 6) + lane] = C[(size_t)g * SORT_N + (g << 6) + lane];
        ldsC1[(g << 6) + lane] =
            (g < 63) ? C[(size_t)(g + 1) * SORT_N + (g << 6) + lane] : 0ull;
    }
    __syncthreads();
    if (wid != 0) return;  // only wave 0 scans; no further block-wide syncs

    u64 rem = 0ull, d1c = 0ull;
    u64 gA[8], gB[8];
#pragma unroll
    for (int k = 0; k < 8; ++k) { gA[k] = 0ull; gB[k] = 0ull; }
    int k0 = 0, k1 = 0, k2 = 0, k3 = 0, k4 = 0;  // kept idx, slot r: lane==r&63, reg j=r>>6
    int kcnt = 0;
    bool done = false;
    u64 nDg = ldsDiag[lane];
    u64 nC1 = ldsC1[lane];

    for (int g = 0; g < 64; ++g) {
        u64 Dg = nDg, c1r = nC1;
        if (g < 63) {
            nDg = ldsDiag[((g + 1) << 6) + lane];
            nC1 = ldsC1[((g + 1) << 6) + lane];
        }
        // retire generation A (rows issued at end of group g-2)
        rem |= ((gA[0] | gA[1]) | (gA[2] | gA[3])) |
               ((gA[4] | gA[5]) | (gA[6] | gA[7]));
#pragma unroll
        for (int k = 0; k < 8; ++k) { gA[k] = gB[k]; gB[k] = 0ull; }

        u64 cur = rl64(rem, g) | d1c;
        u64 pending = ~cur;
        u64 alive = 0ull;
        while (pending) {
            int bit = __builtin_ctzll(pending);
            int i = (g << 6) + bit;
            if (lane == (kcnt & 63)) {
                switch (kcnt >> 6) {
                    case 0: k0 = i; break;
                    case 1: k1 = i; break;
                    case 2: k2 = i; break;
                    case 3: k3 = i; break;
                    default: k4 = i; break;
                }
            }
            ++kcnt;
            alive |= 1ull << bit;
            if (kcnt == POST_NMS) { done = true; break; }
            u64 d = rl64(Dg, bit);
            pending &= ~(d | (1ull << bit));
        }
        if (done) break;

        // carry: suppression of group g's kept boxes on group g+1
        u64 s1 = 0ull;
        u64 am = alive;
        while (am) {
            int i = __builtin_ctzll(am);
            am &= am - 1;
            s1 |= rl64(c1r, i);
        }
        d1c = s1;

        // issue coalesced row loads for kept rows -> generation B
        u64 am2 = alive;
        if (am2) {
            int i0 = __builtin_ctzll(am2);
            am2 &= am2 - 1;
            int idx[8];
            idx[0] = i0;
#pragma unroll
            for (int k = 1; k < 8; ++k) {
                idx[k] = am2 ? __builtin_ctzll(am2) : i0;
                am2 = am2 ? (am2 & (am2 - 1)) : 0ull;
            }
            size_t base = (size_t)g << 6;
#pragma unroll
            for (int k = 0; k < 8; ++k)
                gB[k] = R[(base + idx[k]) * MASK_WORDS + lane];
            while (am2) {  // >8 kept in one group: rare
                int j = __builtin_ctzll(am2);
                am2 &= am2 - 1;
                gB[0] |= R[(base + j) * MASK_WORDS + lane];
            }
        }
    }

    // output: row r handled by lane r&63, register slot r>>6
#pragma unroll
    for (int j = 0; j < 5; ++j) {
        int r = (j << 6) + lane;
        if (r < POST_NMS) {
            int idx = (j == 0) ? k0 : (j == 1) ? k1 : (j == 2) ? k2 : (j == 3) ? k3 : k4;
            float4 bx = make_float4(0.f, 0.f, 0.f, 0.f);
            if (r < kcnt) bx = sortedBoxes[(size_t)b * SORT_N + idx];
            float* o = out + ((size_t)b * POST_NMS + r) * 5;
            o[0] = (float)b;
            o[1] = bx.x;
            o[2] = bx.y;
            o[3] = bx.z;
            o[4] = bx.w;
        }
    }
}

// ---------------------------------------------------------------------------
extern "C" void kernel_launch(void* const* d_in, const int* in_sizes, int n_in,
                              void* d_out, int out_size, void* d_ws, size_t ws_size,
                              hipStream_t stream) {
    const float* scores  = (const float*)d_in[0];
    const float* deltas  = (const float*)d_in[1];
    const float* im_info = (const float*)d_in[2];
    const float* anchors = (const float*)d_in[3];
    float* out = (float*)d_out;

    char* ws = (char*)d_ws;
    size_t off = 0;
    // persistent across the whole pipeline:
    float4* sortedBoxes = (float4*)(ws + off);
    off += (size_t)B_N * SORT_N * sizeof(float4);
    off = (off + 255) & ~(size_t)255;
    u64* colmaj = (u64*)(ws + off);
    off += (size_t)B_N * MASK_WORDS * SORT_N * sizeof(u64);
    off = (off + 255) & ~(size_t)255;
    // rowmaj ALIASES the early-phase buffers (boxes/keys/cand/ghist/cnt/T are
    // all dead before iou_mask writes rowmaj; stream order guarantees safety).
    u64* rowmaj = (u64*)(ws + off);
    size_t early = off;
    off += (size_t)B_N * SORT_N * MASK_WORDS * sizeof(u64);

    float4* boxes = (float4*)(ws + early);
    early += (size_t)B_N * N_PROP * sizeof(float4);
    early = (early + 255) & ~(size_t)255;
    u64* keys = (u64*)(ws + early);
    early += (size_t)B_N * N_PROP * sizeof(u64);
    early = (early + 255) & ~(size_t)255;
    u64* cand = (u64*)(ws + early);
    early += (size_t)B_N * CAND_MAX * sizeof(u64);
    early = (early + 255) & ~(size_t)255;
    unsigned* ghist = (unsigned*)(ws + early);
    size_t zero_off = early;
    early += (size_t)B_N * NBINS * sizeof(unsigned);
    unsigned* cnt = (unsigned*)(ws + early);
    early += (size_t)B_N * sizeof(unsigned);
    size_t zero_bytes = early - zero_off;
    early = (early + 255) & ~(size_t)255;
    int* Tbuf = (int*)(ws + early);
    early += (size_t)B_N * sizeof(int);
    // early-phase end must fit inside rowmaj (8 MB): ~4.4 MB used. OK.

    hipMemsetAsync((void*)ghist, 0, zero_bytes, stream);

    int total = B_N * N_PROP;
    decode_kernel<<<(total + 255) / 256, 256, 0, stream>>>(
        scores, deltas, im_info, anchors, boxes, keys, ghist);
    findT_kernel<<<B_N, 64, 0, stream>>>(ghist, Tbuf);
    compact_kernel<<<dim3((N_PROP + 255) / 256, B_N), 256, 0, stream>>>(
        keys, Tbuf, cnt, cand);
    rank_scatter_kernel<<<dim3(CAND_MAX / 64, B_N), 256, 0, stream>>>(
        cand, cnt, boxes, sortedBoxes);
    iou_mask_kernel<<<dim3(64, 64, B_N), 64, 0, stream>>>(sortedBoxes, colmaj, rowmaj);
    nms_scan_kernel<<<B_N, 256, 65536, stream>>>(colmaj, rowmaj, sortedBoxes, out);
}